// Round 16
// baseline (75.831 us; speedup 1.0000x reference)
//
#include <hip/hip_runtime.h>

// Problem constants (B,C,H,W,K) = (32,192,56,56,7)
#define BB 32
#define CC 192
#define HH 56
#define WW 56
#define KS 7
#define HW 3136        // 56*56
#define KK 49
#define CKK 9408       // C*K*K
#define PL 8
#define NCELL (BB * CC * KK)   // 301056
#define NBC (BB * CC)          // 6144
#define P0BLK 37               // pool blocks per sample
#define MIDBLK 24              // mid blocks per sample
#define KSTRIDE 52             // padded tap row stride (16B-aligned rows)

typedef float f2 __attribute__((ext_vector_type(2)));

// ---------------------------------------------------------------------------
// K1: avg pool 56x56 -> 7x7 + per-block LN0 partials (no atomics).
// ---------------------------------------------------------------------------
__global__ __launch_bounds__(256) void pool_kernel(const float* __restrict__ x,
                                                   float* __restrict__ p0,
                                                   float2* __restrict__ part0) {
    __shared__ float red[8];
    int b = blockIdx.x / P0BLK;
    int t = blockIdx.x - b * P0BLK;
    int cell = t * 256 + threadIdx.x;
    float v = 0.f;
    if (cell < CKK) {
        int c = cell / KK;
        int r = cell - c * KK;
        int i = r / KS;
        int j = r - i * KS;
        const float* src = x + ((size_t)(b * CC + c)) * HW + (i * PL) * WW + j * PL;
        float s = 0.f;
#pragma unroll
        for (int a = 0; a < PL; ++a) {
            float4 v0 = *(const float4*)(src + a * WW);
            float4 v1 = *(const float4*)(src + a * WW + 4);
            s += v0.x + v0.y + v0.z + v0.w + v1.x + v1.y + v1.z + v1.w;
        }
        v = s * (1.f / 64.f);
        p0[b * CKK + cell] = v;
    }
    float sv = v, sq = v * v;
#pragma unroll
    for (int o = 32; o > 0; o >>= 1) {
        sv += __shfl_down(sv, o, 64);
        sq += __shfl_down(sq, o, 64);
    }
    if ((threadIdx.x & 63) == 0) {
        red[(threadIdx.x >> 6) * 2 + 0] = sv;
        red[(threadIdx.x >> 6) * 2 + 1] = sq;
    }
    __syncthreads();
    if (threadIdx.x == 0)
        part0[blockIdx.x] = make_float2(red[0] + red[2] + red[4] + red[6],
                                        red[1] + red[3] + red[5] + red[7]);
}

// ---------------------------------------------------------------------------
// K2: LN0-normalize + depthwise 7x7 conv on the 7x7 map, one WAVE per (b,c).
// ---------------------------------------------------------------------------
__global__ __launch_bounds__(512) void mid_kernel(
    const float* __restrict__ p0,
    const float* __restrict__ ln0w, const float* __restrict__ ln0b,
    const float* __restrict__ w0,
    const float2* __restrict__ part0,
    float* __restrict__ q1,
    float2* __restrict__ part1)
{
    __shared__ float red[16];
    int tid  = threadIdx.x;
    int lane = tid & 63;
    int bc   = blockIdx.x * 8 + (tid >> 6);
    int b = bc / CC;
    int c = bc - b * CC;

    float s0 = 0.f, ss0 = 0.f;
    if (lane < P0BLK) {
        float2 p = part0[b * P0BLK + lane];
        s0 = p.x; ss0 = p.y;
    }
#pragma unroll
    for (int o = 32; o > 0; o >>= 1) {
        s0  += __shfl_down(s0, o, 64);
        ss0 += __shfl_down(ss0, o, 64);
    }
    s0  = __shfl(s0, 0, 64);
    ss0 = __shfl(ss0, 0, 64);
    float mean = s0 * (1.f / CKK);
    float rstd = rsqrtf(ss0 * (1.f / CKK) - mean * mean + 1e-5f);

    float val = 0.f;
    if (lane < KK)
        val = (p0[bc * KK + lane] - mean) * rstd * ln0w[c * KK + lane]
              + ln0b[c * KK + lane];

    int i0 = lane / KS;
    int j0 = lane - i0 * KS;
    const float* wc = w0 + c * KK;

    float acc = 0.f;
#pragma unroll
    for (int u = 0; u < KS; ++u) {
        int ii = i0 + u - 3;
#pragma unroll
        for (int v = 0; v < KS; ++v) {
            int jj = j0 + v - 3;
            bool ok = (ii >= 0) && (ii < KS) && (jj >= 0) && (jj < KS);
            int sl = ok ? (ii * KS + jj) : 0;
            float sv = __shfl(val, sl, 64);
            acc += ok ? sv * wc[u * KS + v] : 0.f;
        }
    }
    if (lane >= KK) acc = 0.f;
    if (lane < KK) q1[bc * KK + lane] = acc;

    float s2 = acc, ss2 = acc * acc;
#pragma unroll
    for (int o = 32; o > 0; o >>= 1) {
        s2  += __shfl_down(s2, o, 64);
        ss2 += __shfl_down(ss2, o, 64);
    }
    if (lane == 0) {
        red[(tid >> 6) * 2 + 0] = s2;
        red[(tid >> 6) * 2 + 1] = ss2;
    }
    __syncthreads();
    if (tid == 0) {
        float a = 0.f, q = 0.f;
#pragma unroll
        for (int w = 0; w < 8; ++w) { a += red[2 * w]; q += red[2 * w + 1]; }
        part1[blockIdx.x] = make_float2(a, q);
    }
}

// ---------------------------------------------------------------------------
// K3: tab_kernel — LN1+ReLU taps, one wave per bc -> ktab[bc][52] (plain).
// ---------------------------------------------------------------------------
__global__ __launch_bounds__(256) void tab_kernel(
    const float* __restrict__ q1, const float2* __restrict__ part1,
    const float* __restrict__ ln1w, const float* __restrict__ ln1b,
    float* __restrict__ ktab)
{
    int lane = threadIdx.x & 63;
    int bc   = blockIdx.x * 4 + (threadIdx.x >> 6);
    int b = bc / CC;
    int c = bc - b * CC;

    float s1 = 0.f, ss1 = 0.f;
    if (lane < MIDBLK) {
        float2 p = part1[b * MIDBLK + lane];
        s1 = p.x; ss1 = p.y;
    }
#pragma unroll
    for (int o = 32; o > 0; o >>= 1) {
        s1  += __shfl_down(s1, o, 64);
        ss1 += __shfl_down(ss1, o, 64);
    }
    s1  = __shfl(s1, 0, 64);
    ss1 = __shfl(ss1, 0, 64);
    float m = s1 * (1.f / CKK);
    float r = rsqrtf(ss1 * (1.f / CKK) - m * m + 1e-5f);

    if (lane < KK) {
        float v = (q1[(size_t)bc * KK + lane] - m) * r * ln1w[c * KK + lane]
                  + ln1b[c * KK + lane];
        ktab[(size_t)bc * KSTRIDE + lane] = v > 0.f ? v : 0.f;
    }
}

// ---------------------------------------------------------------------------
// K4: per-(b,c) depthwise 7x7 SAME conv — WAVE-AUTONOMOUS, ZERO BARRIERS.
// Each wave owns a 14-row strip: stages its own 20 input rows into a private
// 5 KB LDS region (rowpair k = x rows {r0-3+2k, r0-2+2k} packed as f2, lane =
// column, left-pad 3), then computes via the verified rowpair decomposition
// with plain v_fmac + SGPR taps: per (s,d): output-lo gets taps {2d,2d+1},
// output-hi gets {2d-1,2d} -> exactly 686 fmac/lane. No __syncthreads at all:
// producer wave == consumer wave (lgkmcnt orders LDS within a wave).
// ---------------------------------------------------------------------------
__device__ __forceinline__ float rfl(float v) {
    return __int_as_float(__builtin_amdgcn_readfirstlane(__float_as_int(v)));
}

__global__ __launch_bounds__(256) void conv_kernel(
    const float* __restrict__ x,
    const float* __restrict__ ktab,
    float* __restrict__ out)
{
    __shared__ f2 wl[4][10 * 64];      // 5 KB per wave, 20 KB per block
    int bc   = blockIdx.x;
    int tid  = threadIdx.x;
    int lane = tid & 63;
    int wid  = tid >> 6;

    // ---- taps -> SGPRs (uniform address -> scalarized loads), issue first ----
    const float* kp = ktab + (size_t)bc * KSTRIDE;
    float tap[KK];
#pragma unroll
    for (int t = 0; t < KK; ++t) tap[t] = rfl(kp[t]);

    // ---- wave-private staging: lane = cell = x col (lane-3), 20 rows ----
    const float* src = x + (size_t)bc * HW;
    int r0   = wid * 14;
    int colx = lane - 3;
    bool colok = (colx >= 0) && (colx < WW);
    f2* wlp = wl[wid];
#pragma unroll
    for (int k = 0; k < 10; ++k) {
        int rlo = r0 - 3 + 2 * k;
        int rhi = rlo + 1;
        float vlo = 0.f, vhi = 0.f;
        if (colok && rlo >= 0 && rlo < HH) vlo = src[rlo * WW + colx];
        if (colok && rhi >= 0 && rhi < HH) vhi = src[rhi * WW + colx];
        wlp[k * 64 + lane] = (f2){vlo, vhi};
    }
    // wave-internal producer->consumer ordering (no block barrier needed)
    asm volatile("s_waitcnt lgkmcnt(0)" ::: "memory");
    __builtin_amdgcn_sched_barrier(0);

    // ---- main loop: 10 rowpair steps, accumulator forwarding, scalar fmac ----
    float accL[7], accH[7];
#pragma unroll
    for (int t = 0; t < 7; ++t) { accL[t] = 0.f; accH[t] = 0.f; }

#pragma unroll
    for (int s = 0; s < 10; ++s) {
        const f2* cp = wlp + s * 64 + lane;
        f2 v[KS];
#pragma unroll
        for (int j = 0; j < KS; ++j) v[j] = cp[j];   // ds_read_b64, same-row
#pragma unroll
        for (int d = 0; d < 4; ++d) {
            int t = s - d;                           // static after unroll
            if (t < 0 || t > 6) continue;
#pragma unroll
            for (int vv = 0; vv < KS; ++vv) {
                // output row lo (r0+2t): taps u=2d (from row lo), u=2d+1 (hi)
                accL[t] = fmaf(v[vv].x, tap[2 * d * KS + vv], accL[t]);
                if (2 * d + 1 <= 6)
                    accL[t] = fmaf(v[vv].y, tap[(2 * d + 1) * KS + vv], accL[t]);
                // output row hi (r0+2t+1): taps u=2d-1 (from lo), u=2d (hi)
                if (2 * d - 1 >= 0)
                    accH[t] = fmaf(v[vv].x, tap[(2 * d - 1) * KS + vv], accH[t]);
                accH[t] = fmaf(v[vv].y, tap[2 * d * KS + vv], accH[t]);
            }
        }
    }

    if (lane < WW) {
        float* ob = out + (size_t)bc * HW + r0 * WW + lane;
#pragma unroll
        for (int t = 0; t < 7; ++t) {
            ob[(2 * t) * WW]     = accL[t];
            ob[(2 * t + 1) * WW] = accH[t];
        }
    }
}

// ---------------------------------------------------------------------------
extern "C" void kernel_launch(void* const* d_in, const int* in_sizes, int n_in,
                              void* d_out, int out_size, void* d_ws, size_t ws_size,
                              hipStream_t stream) {
    const float* x    = (const float*)d_in[0];
    const float* ln0w = (const float*)d_in[1];
    const float* ln0b = (const float*)d_in[2];
    const float* w0   = (const float*)d_in[3];
    const float* ln1w = (const float*)d_in[4];
    const float* ln1b = (const float*)d_in[5];
    float* out = (float*)d_out;

    float*  p0    = (float*)d_ws;                    // [NCELL]
    float*  q1    = p0 + NCELL;                      // [NCELL]
    float2* part0 = (float2*)(q1 + NCELL);           // [BB*P0BLK]
    float2* part1 = part0 + BB * P0BLK;              // [BB*MIDBLK]
    float*  ktab  = (float*)(part1 + BB * MIDBLK);   // [NBC*KSTRIDE]

    pool_kernel<<<BB * P0BLK, 256, 0, stream>>>(x, p0, part0);
    mid_kernel <<<BB * MIDBLK, 512, 0, stream>>>(p0, ln0w, ln0b, w0, part0, q1, part1);
    tab_kernel <<<NBC / 4, 256, 0, stream>>>(q1, part1, ln1w, ln1b, ktab);
    conv_kernel<<<NBC, 256, 0, stream>>>(x, ktab, out);
}

// Round 19
// 59.291 us; speedup vs baseline: 1.2789x; 1.2789x over previous
//
#include <hip/hip_runtime.h>

// Problem constants (B,C,H,W,K) = (32,192,56,56,7)
#define BB 32
#define CC 192
#define HH 56
#define WW 56
#define KS 7
#define HW 3136        // 56*56
#define KK 49
#define CKK 9408       // C*K*K
#define PL 8
#define NCELL (BB * CC * KK)   // 301056
#define NBC (BB * CC)          // 6144
#define P0BLK 37               // pool blocks per sample
#define MIDBLK 24              // mid blocks per sample
#define TABW 56                // u32 words per channel in tap table

typedef _Float16 h2 __attribute__((ext_vector_type(2)));   // for fdot2 only

__device__ __forceinline__ unsigned int pack16(float a, float b) {
    // v_cvt_pkrtz_f16_f32 -> reinterpret as u32 (avoids __fp16/_Float16 clash)
    return __builtin_bit_cast(unsigned int, __builtin_amdgcn_cvt_pkrtz(a, b));
}

// ---------------------------------------------------------------------------
// K1: avg pool 56x56 -> 7x7 + per-block LN0 partials (no atomics).
// ---------------------------------------------------------------------------
__global__ __launch_bounds__(256) void pool_kernel(const float* __restrict__ x,
                                                   float* __restrict__ p0,
                                                   float2* __restrict__ part0) {
    __shared__ float red[8];
    int b = blockIdx.x / P0BLK;
    int t = blockIdx.x - b * P0BLK;
    int cell = t * 256 + threadIdx.x;
    float v = 0.f;
    if (cell < CKK) {
        int c = cell / KK;
        int r = cell - c * KK;
        int i = r / KS;
        int j = r - i * KS;
        const float* src = x + ((size_t)(b * CC + c)) * HW + (i * PL) * WW + j * PL;
        float s = 0.f;
#pragma unroll
        for (int a = 0; a < PL; ++a) {
            float4 v0 = *(const float4*)(src + a * WW);
            float4 v1 = *(const float4*)(src + a * WW + 4);
            s += v0.x + v0.y + v0.z + v0.w + v1.x + v1.y + v1.z + v1.w;
        }
        v = s * (1.f / 64.f);
        p0[b * CKK + cell] = v;
    }
    float sv = v, sq = v * v;
#pragma unroll
    for (int o = 32; o > 0; o >>= 1) {
        sv += __shfl_down(sv, o, 64);
        sq += __shfl_down(sq, o, 64);
    }
    if ((threadIdx.x & 63) == 0) {
        red[(threadIdx.x >> 6) * 2 + 0] = sv;
        red[(threadIdx.x >> 6) * 2 + 1] = sq;
    }
    __syncthreads();
    if (threadIdx.x == 0)
        part0[blockIdx.x] = make_float2(red[0] + red[2] + red[4] + red[6],
                                        red[1] + red[3] + red[5] + red[7]);
}

// ---------------------------------------------------------------------------
// K2: LN0-normalize + depthwise 7x7 conv on the 7x7 map, one WAVE per (b,c).
// ---------------------------------------------------------------------------
__global__ __launch_bounds__(512) void mid_kernel(
    const float* __restrict__ p0,
    const float* __restrict__ ln0w, const float* __restrict__ ln0b,
    const float* __restrict__ w0,
    const float2* __restrict__ part0,
    float* __restrict__ q1,
    float2* __restrict__ part1)
{
    __shared__ float red[16];
    int tid  = threadIdx.x;
    int lane = tid & 63;
    int bc   = blockIdx.x * 8 + (tid >> 6);
    int b = bc / CC;
    int c = bc - b * CC;

    float s0 = 0.f, ss0 = 0.f;
    if (lane < P0BLK) {
        float2 p = part0[b * P0BLK + lane];
        s0 = p.x; ss0 = p.y;
    }
#pragma unroll
    for (int o = 32; o > 0; o >>= 1) {
        s0  += __shfl_down(s0, o, 64);
        ss0 += __shfl_down(ss0, o, 64);
    }
    s0  = __shfl(s0, 0, 64);
    ss0 = __shfl(ss0, 0, 64);
    float mean = s0 * (1.f / CKK);
    float rstd = rsqrtf(ss0 * (1.f / CKK) - mean * mean + 1e-5f);

    float val = 0.f;
    if (lane < KK)
        val = (p0[bc * KK + lane] - mean) * rstd * ln0w[c * KK + lane]
              + ln0b[c * KK + lane];

    int i0 = lane / KS;
    int j0 = lane - i0 * KS;
    const float* wc = w0 + c * KK;

    float acc = 0.f;
#pragma unroll
    for (int u = 0; u < KS; ++u) {
        int ii = i0 + u - 3;
#pragma unroll
        for (int v = 0; v < KS; ++v) {
            int jj = j0 + v - 3;
            bool ok = (ii >= 0) && (ii < KS) && (jj >= 0) && (jj < KS);
            int sl = ok ? (ii * KS + jj) : 0;
            float sv = __shfl(val, sl, 64);
            acc += ok ? sv * wc[u * KS + v] : 0.f;
        }
    }
    if (lane >= KK) acc = 0.f;
    if (lane < KK) q1[bc * KK + lane] = acc;

    float s2 = acc, ss2 = acc * acc;
#pragma unroll
    for (int o = 32; o > 0; o >>= 1) {
        s2  += __shfl_down(s2, o, 64);
        ss2 += __shfl_down(ss2, o, 64);
    }
    if (lane == 0) {
        red[(tid >> 6) * 2 + 0] = s2;
        red[(tid >> 6) * 2 + 1] = ss2;
    }
    __syncthreads();
    if (tid == 0) {
        float a = 0.f, q = 0.f;
#pragma unroll
        for (int w = 0; w < 8; ++w) { a += red[2 * w]; q += red[2 * w + 1]; }
        part1[blockIdx.x] = make_float2(a, q);
    }
}

// ---------------------------------------------------------------------------
// K3: tab_kernel — LN1+ReLU taps -> h2 tap-pair tables (one wave per bc).
//   ktab[bc][0..27]  dt[d*7+v] = h2{kt[2d*7+v],  d<3 ? kt[(2d+1)*7+v] : 0}
//   ktab[bc][28..55] ct[d*7+v] = h2{d>0 ? kt[(2d-1)*7+v] : 0, kt[2d*7+v]}
// ---------------------------------------------------------------------------
__global__ __launch_bounds__(256) void tab_kernel(
    const float* __restrict__ q1, const float2* __restrict__ part1,
    const float* __restrict__ ln1w, const float* __restrict__ ln1b,
    unsigned int* __restrict__ ktab)
{
    int lane = threadIdx.x & 63;
    int bc   = blockIdx.x * 4 + (threadIdx.x >> 6);
    int b = bc / CC;
    int c = bc - b * CC;

    float s1 = 0.f, ss1 = 0.f;
    if (lane < MIDBLK) {
        float2 p = part1[b * MIDBLK + lane];
        s1 = p.x; ss1 = p.y;
    }
#pragma unroll
    for (int o = 32; o > 0; o >>= 1) {
        s1  += __shfl_down(s1, o, 64);
        ss1 += __shfl_down(ss1, o, 64);
    }
    s1  = __shfl(s1, 0, 64);
    ss1 = __shfl(ss1, 0, 64);
    float m = s1 * (1.f / CKK);
    float r = rsqrtf(ss1 * (1.f / CKK) - m * m + 1e-5f);

    float kt = 0.f;
    if (lane < KK) {
        float v = (q1[(size_t)bc * KK + lane] - m) * r * ln1w[c * KK + lane]
                  + ln1b[c * KK + lane];
        kt = v > 0.f ? v : 0.f;
    }

    bool isDt = lane < 28;
    int idx = isDt ? lane : (lane < TABW ? lane - 28 : 0);
    int d = idx / KS, v = idx - KS * d;
    int i0 = 2 * d * KS + v;                    // 0..48
    int ip = i0 + KS > 48 ? 48 : i0 + KS;
    int im = i0 - KS < 0  ? 0  : i0 - KS;
    float vi0 = __shfl(kt, i0, 64);
    float vip = __shfl(kt, ip, 64);
    float vim = __shfl(kt, im, 64);
    float a = isDt ? vi0 : (d > 0 ? vim : 0.f);
    float bb = isDt ? (d < 3 ? vip : 0.f) : vi0;
    unsigned int w = pack16(a, bb);
    if (lane < TABW)
        ktab[(size_t)bc * TABW + lane] = w;
}

// ---------------------------------------------------------------------------
// K4: per-(b,c) depthwise 7x7 SAME conv — f16 rowpair LDS + v_dot2_f32_f16.
// Tile word (pr2, cw) = h2{ x[2*pr2-3][cw-4], x[2*pr2-2][cw-4] } (0 outside).
// Lane owns output col `lane`; window = words lane+1..lane+7 of rowpair s.
// Per (s,d) with t=s-d in [0,6]: accL[t] += dot2(w, dt[d][v]),
// accH[t] += dot2(w, ct[d][v]) -> 392 dot2 = 784 MAC-issue cyc/wave.
// FIX vs R18: halo-zero ranges now both fit in 256 threads (the else-if
// chain left rowpair 29's edge words uninitialized -> absmax 19).
// ---------------------------------------------------------------------------
__global__ __launch_bounds__(256) void conv_kernel(
    const float* __restrict__ x,
    const unsigned int* __restrict__ ktab,
    float* __restrict__ out)
{
    __shared__ unsigned int tile[32 * 64];   // 8 KB
    int bc   = blockIdx.x;
    int tid  = threadIdx.x;
    int lane = tid & 63;
    int wid  = tid >> 6;

    // ---- tap-pair tables (block-uniform -> s_load / SGPRs) ----
    const uint4* tb = (const uint4*)(ktab + (size_t)bc * TABW);
    unsigned int dt[28], ct[28];
#pragma unroll
    for (int i = 0; i < 7; ++i) {
        uint4 t4 = tb[i];
        dt[4 * i + 0] = t4.x; dt[4 * i + 1] = t4.y;
        dt[4 * i + 2] = t4.z; dt[4 * i + 3] = t4.w;
    }
#pragma unroll
    for (int i = 0; i < 7; ++i) {
        uint4 t4 = tb[7 + i];
        ct[4 * i + 0] = t4.x; ct[4 * i + 1] = t4.y;
        ct[4 * i + 2] = t4.z; ct[4 * i + 3] = t4.w;
    }

    // ---- issue global stage loads (tasks: pr2 1..29 x 14 col-quads) ----
    const float* src = x + (size_t)bc * HW;
    int t0 = tid, t1 = tid + 256;
    int pr2a = 1 + t0 / 14, qa = t0 - (pr2a - 1) * 14;
    int pr2b = 1 + t1 / 14, qb = t1 - (pr2b - 1) * 14;
    bool has1 = t1 < 29 * 14;
    int rAa = 2 * pr2a - 3, rBa = rAa + 1;       // rAa in [-1,35], rBa in [0,36]
    int rAb = 2 * pr2b - 3, rBb = rAb + 1;       // rAb in [35,55], rBb in [36,56]
    float4 z4 = make_float4(0.f, 0.f, 0.f, 0.f);
    float4 a0 = (rAa >= 0) ? *(const float4*)(src + rAa * WW + 4 * qa) : z4;
    float4 b0 = *(const float4*)(src + rBa * WW + 4 * qa);
    float4 a1 = z4, b1 = z4;
    if (has1) {
        a1 = *(const float4*)(src + rAb * WW + 4 * qb);
        b1 = (rBb < HH) ? *(const float4*)(src + rBb * WW + 4 * qb) : z4;
    }

    // ---- halo zero (two independent ranges, both fit in 256 threads) ----
    if (tid < 232) {                   // edge words 0-3 & 60-63 of rowpairs 1..29
        int pr2 = 1 + (tid >> 3);
        int j = tid & 7;
        tile[pr2 * 64 + (j < 4 ? j : 56 + j)] = 0u;
    }
    if (tid >= 224) {                  // rowpairs 0 & 30 full width (32 x b128)
        int i = tid - 224;             // 0..31
        int pr2 = (i < 16) ? 0 : 30;
        *(uint4*)(tile + pr2 * 64 + 4 * (i & 15)) = make_uint4(0, 0, 0, 0);
    }

    // ---- pack + staged writes (one ds_write_b128 per task) ----
    {
        *(uint4*)(tile + pr2a * 64 + 4 + 4 * qa) =
            make_uint4(pack16(a0.x, b0.x), pack16(a0.y, b0.y),
                       pack16(a0.z, b0.z), pack16(a0.w, b0.w));
    }
    if (has1) {
        *(uint4*)(tile + pr2b * 64 + 4 + 4 * qb) =
            make_uint4(pack16(a1.x, b1.x), pack16(a1.y, b1.y),
                       pack16(a1.z, b1.z), pack16(a1.w, b1.w));
    }
    __syncthreads();

    // ---- main loop: ping-pong prefetch, rowpair dot2 algebra ----
    int r0 = wid * 14;
    const unsigned int* base = tile + (wid * 7) * 64 + lane + 1;
    float accL[7], accH[7];
#pragma unroll
    for (int t = 0; t < 7; ++t) { accL[t] = 0.f; accH[t] = 0.f; }

    unsigned int wa[KS], wb[KS];
#pragma unroll
    for (int j = 0; j < KS; ++j) wa[j] = base[j];          // rowpair s=0

#define H2(u) __builtin_bit_cast(h2, (u))
#define CONV_STEP(S, CUR)                                                     \
    {                                                                         \
        _Pragma("unroll")                                                     \
        for (int d = 0; d < 4; ++d) {                                         \
            int t = (S) - d;                                                  \
            if (t >= 0 && t <= 6) {                                           \
                _Pragma("unroll")                                             \
                for (int vv = 0; vv < KS; ++vv) {                             \
                    accL[t] = __builtin_amdgcn_fdot2(H2(CUR[vv]),             \
                                  H2(dt[d * KS + vv]), accL[t], false);       \
                    accH[t] = __builtin_amdgcn_fdot2(H2(CUR[vv]),             \
                                  H2(ct[d * KS + vv]), accH[t], false);       \
                }                                                             \
            }                                                                 \
        }                                                                     \
    }

#pragma unroll
    for (int ss = 0; ss < 5; ++ss) {
        int s0 = 2 * ss, s1 = 2 * ss + 1;
        {
            const unsigned int* np = base + s1 * 64;
#pragma unroll
            for (int j = 0; j < KS; ++j) wb[j] = np[j];
        }
        CONV_STEP(s0, wa);
        if (ss < 4) {
            const unsigned int* np = base + (s0 + 2) * 64;
#pragma unroll
            for (int j = 0; j < KS; ++j) wa[j] = np[j];
        }
        CONV_STEP(s1, wb);
    }
#undef CONV_STEP
#undef H2

    if (lane < WW) {
        float* ob = out + (size_t)bc * HW + r0 * WW + lane;
#pragma unroll
        for (int t = 0; t < 7; ++t) {
            ob[(2 * t) * WW]     = accL[t];
            ob[(2 * t + 1) * WW] = accH[t];
        }
    }
}

// ---------------------------------------------------------------------------
extern "C" void kernel_launch(void* const* d_in, const int* in_sizes, int n_in,
                              void* d_out, int out_size, void* d_ws, size_t ws_size,
                              hipStream_t stream) {
    const float* x    = (const float*)d_in[0];
    const float* ln0w = (const float*)d_in[1];
    const float* ln0b = (const float*)d_in[2];
    const float* w0   = (const float*)d_in[3];
    const float* ln1w = (const float*)d_in[4];
    const float* ln1b = (const float*)d_in[5];
    float* out = (float*)d_out;

    float*  p0    = (float*)d_ws;                     // [NCELL]
    float*  q1    = p0 + NCELL;                       // [NCELL]
    float2* part0 = (float2*)(q1 + NCELL);            // [BB*P0BLK]
    float2* part1 = part0 + BB * P0BLK;               // [BB*MIDBLK]
    unsigned int* ktab = (unsigned int*)(part1 + BB * MIDBLK);   // [NBC*TABW]

    pool_kernel<<<BB * P0BLK, 256, 0, stream>>>(x, p0, part0);
    mid_kernel <<<BB * MIDBLK, 512, 0, stream>>>(p0, ln0w, ln0b, w0, part0, q1, part1);
    tab_kernel <<<NBC / 4, 256, 0, stream>>>(q1, part1, ln1w, ln1b, ktab);
    conv_kernel<<<NBC, 256, 0, stream>>>(x, ktab, out);
}